// Round 1
// baseline (349.723 us; speedup 1.0000x reference)
//
#include <hip/hip_runtime.h>

// HDCProcessor: trigram-bind over bipolar codebook + causal exp-decay matmul.
// Key identities:
//   hdc[b,t,d] = s1*(0.7*s2*s3 + 0.3), s* in {+1,-1}  -> values {±1.0, ∓0.4}
//   hdc[b,t,d] = 0.3*s1 for t<2 (rolled rows zeroed)
//   out[t] = U[t]*(1-DEC)/(1-DEC^{t+1}), U[t] = DEC*U[t-1] + hdc[t]   (scan!)
// Bit-pack codebook signs (plus pre-shifted-by-1/2 copies so the D-axis roll
// becomes a same-index byte load). Chunk T with a 192-step warmup (0.95^193
// ~ 5e-5 normalized truncation error, far below threshold).

#define VOCAB   256
#define D_      4096
#define T_      2048
#define B_      8
#define DEC     0.95f
#define CHUNK   128
#define WARM    192
#define NCH     (T_/CHUNK)        // 16
#define THREADS 128
#define DGRP    (D_/(THREADS*8))  // 4  (each thread owns 8 consecutive d's)
#define ROWB    (D_/8)            // 512 bytes per packed row

// Static device scratch (avoids relying on ws_size); rewritten every call.
__device__ unsigned char g_P1[VOCAB*ROWB];
__device__ unsigned char g_P2[VOCAB*ROWB];  // signs shifted by 1 along D (mod D)
__device__ unsigned char g_P3[VOCAB*ROWB];  // signs shifted by 2 along D (mod D)

__global__ __launch_bounds__(256) void pack_kernel(const float* __restrict__ cb) {
    int gid = blockIdx.x * 256 + threadIdx.x;     // 0 .. VOCAB*ROWB-1
    int r   = gid >> 9;                           // row (512 bytes/row)
    int byt = gid & 511;
    const float* row = cb + r * D_;
    unsigned b1 = 0, b2 = 0, b3 = 0;
#pragma unroll
    for (int j = 0; j < 8; ++j) {
        int d = byt * 8 + j;
        unsigned s1 = __float_as_uint(row[d]) >> 31;
        unsigned s2 = __float_as_uint(row[(d - 1) & (D_ - 1)]) >> 31;
        unsigned s3 = __float_as_uint(row[(d - 2) & (D_ - 1)]) >> 31;
        b1 |= s1 << j; b2 |= s2 << j; b3 |= s3 << j;
    }
    g_P1[gid] = (unsigned char)b1;
    g_P2[gid] = (unsigned char)b2;
    g_P3[gid] = (unsigned char)b3;
}

__global__ __launch_bounds__(THREADS) void hdc_kernel(const int* __restrict__ idx,
                                                      float* __restrict__ out) {
    const int b  = blockIdx.z;
    const int ch = blockIdx.y;
    const int dg = blockIdx.x;
    const int t0 = ch * CHUNK;
    const int ts = (t0 - WARM > 0) ? (t0 - WARM) : 0;
    const int t1 = t0 + CHUNK;
    const int lo = (ts - 2 > 0) ? (ts - 2) : 0;

    __shared__ int sidx[CHUNK + WARM + 2];
    for (int t = lo + threadIdx.x; t < t1; t += THREADS)
        sidx[t - lo] = idx[b * T_ + t];
    __syncthreads();

    const int i = dg * THREADS + threadIdx.x;     // byte index within packed row

    float acc[8];
#pragma unroll
    for (int j = 0; j < 8; ++j) acc[j] = 0.0f;

    // ---- warmup: scan only, no stores, no normalization ----
    const int wsteps = t0 - ts;                   // 0, 128, or 192
#pragma unroll 4
    for (int k = 0; k < wsteps; ++k) {
        int t = ts + k;
        int r1 = sidx[t - lo];
        unsigned ub1 = g_P1[r1 * ROWB + i];
        unsigned n8 = 0;
        float magp = 1.0f, magn = -0.4f;
        if (t >= 2) {
            int r2 = sidx[t - 1 - lo], r3 = sidx[t - 2 - lo];
            n8 = (unsigned)(g_P2[r2 * ROWB + i] ^ g_P3[r3 * ROWB + i]);
        } else {
            magp = 0.3f; magn = 0.3f;
        }
#pragma unroll
        for (int j = 0; j < 8; ++j) {
            float mag    = ((n8 >> j) & 1u) ? magn : magp;
            unsigned sgn = (ub1 << (31 - j)) & 0x80000000u;
            float v      = __uint_as_float(__float_as_uint(mag) ^ sgn);
            acc[j] = fmaf(acc[j], DEC, v);
        }
    }

    // ---- output region ----
    float qn = powf(DEC, (float)(t0 + 1));        // DEC^{t+1} at t = t0
    float* ob = out + (size_t)(b * T_) * D_ + (size_t)i * 8;
#pragma unroll 2
    for (int k = 0; k < CHUNK; ++k) {
        int t = t0 + k;
        int r1 = sidx[t - lo];
        unsigned ub1 = g_P1[r1 * ROWB + i];
        unsigned n8 = 0;
        float magp = 1.0f, magn = -0.4f;
        if (t >= 2) {
            int r2 = sidx[t - 1 - lo], r3 = sidx[t - 2 - lo];
            n8 = (unsigned)(g_P2[r2 * ROWB + i] ^ g_P3[r3 * ROWB + i]);
        } else {
            magp = 0.3f; magn = 0.3f;
        }
        float invn = (1.0f - DEC) / (1.0f - qn);
        float res[8];
#pragma unroll
        for (int j = 0; j < 8; ++j) {
            float mag    = ((n8 >> j) & 1u) ? magn : magp;
            unsigned sgn = (ub1 << (31 - j)) & 0x80000000u;
            float v      = __uint_as_float(__float_as_uint(mag) ^ sgn);
            acc[j] = fmaf(acc[j], DEC, v);
            res[j] = acc[j] * invn;
        }
        float4* o = (float4*)(ob + (size_t)t * D_);
        o[0] = make_float4(res[0], res[1], res[2], res[3]);
        o[1] = make_float4(res[4], res[5], res[6], res[7]);
        qn *= DEC;
    }
}

extern "C" void kernel_launch(void* const* d_in, const int* in_sizes, int n_in,
                              void* d_out, int out_size, void* d_ws, size_t ws_size,
                              hipStream_t stream) {
    const float* cb  = (const float*)d_in[0];   // (256, 4096) fp32
    const int*   idx = (const int*)d_in[1];     // (8, 2048) int32
    float*       out = (float*)d_out;           // (8, 2048, 4096) fp32

    pack_kernel<<<dim3((VOCAB * ROWB) / 256), dim3(256), 0, stream>>>(cb);
    hdc_kernel<<<dim3(DGRP, NCH, B_), dim3(THREADS), 0, stream>>>(idx, out);
}

// Round 2
// 304.320 us; speedup vs baseline: 1.1492x; 1.1492x over previous
//
#include <hip/hip_runtime.h>

// HDCProcessor — exact two-pass chunked scan formulation.
//   hdc[b,t,d] = s1*(0.7*s2*s3 + 0.3) in {±1.0, ∓0.4}; 0.3*s1 for t<2.
//   out[t] = U[t]*(1-DEC)/(1-DEC^{t+1}),  U[t] = DEC*U[t-1] + hdc[t].
// Pass A: per-chunk local scan end-states S.  Pass B: prefix-combine carries.
// Pass C: seeded scan + normalize + store.  Work = 2T per (b,d), exact.

#define VOCAB   256
#define D_      4096
#define T_      2048
#define B_      8
#define DEC     0.95f
#define CHUNK   32
#define NCH     (T_/CHUNK)        // 64
#define THREADS 128
#define DGRP    (D_/(THREADS*8))  // 4  (each thread owns 8 consecutive d's)
#define ROWB    (D_/8)            // 512 bytes per packed row

__device__ unsigned char g_P1[VOCAB*ROWB];
__device__ unsigned char g_P2[VOCAB*ROWB];  // signs shifted by 1 along D
__device__ unsigned char g_P3[VOCAB*ROWB];  // signs shifted by 2 along D
__device__ float g_invn[T_];                // (1-DEC)/(1-DEC^{t+1})
__device__ float g_S[B_*NCH*D_];            // local chunk end states (8 MiB)
__device__ float g_C[B_*NCH*D_];            // entering carries       (8 MiB)

__global__ __launch_bounds__(256) void pack_kernel(const float* __restrict__ cb) {
    int gid = blockIdx.x * 256 + threadIdx.x;     // 0 .. VOCAB*ROWB-1
    int r   = gid >> 9;
    int byt = gid & 511;
    const float* row = cb + r * D_;
    unsigned b1 = 0, b2 = 0, b3 = 0;
#pragma unroll
    for (int j = 0; j < 8; ++j) {
        int d = byt * 8 + j;
        unsigned s1 = __float_as_uint(row[d]) >> 31;
        unsigned s2 = __float_as_uint(row[(d - 1) & (D_ - 1)]) >> 31;
        unsigned s3 = __float_as_uint(row[(d - 2) & (D_ - 1)]) >> 31;
        b1 |= s1 << j; b2 |= s2 << j; b3 |= s3 << j;
    }
    g_P1[gid] = (unsigned char)b1;
    g_P2[gid] = (unsigned char)b2;
    g_P3[gid] = (unsigned char)b3;
    if (gid < T_)
        g_invn[gid] = (1.0f - DEC) / (1.0f - powf(DEC, (float)(gid + 1)));
}

// Per-(b,d)-step bind value: v = ±1.0 or ∓0.4 (or 0.3*s1 for t<2).
__device__ __forceinline__ void bind_step(unsigned ub1, unsigned n8,
                                          float magp, float magn, float* acc) {
#pragma unroll
    for (int j = 0; j < 8; ++j) {
        float mag    = ((n8 >> j) & 1u) ? magn : magp;
        unsigned sgn = (ub1 << (31 - j)) & 0x80000000u;
        float v      = __uint_as_float(__float_as_uint(mag) ^ sgn);
        acc[j] = fmaf(acc[j], DEC, v);
    }
}

__global__ __launch_bounds__(THREADS) void states_kernel(const int* __restrict__ idx) {
    const int b  = blockIdx.z;
    const int ch = blockIdx.y;
    const int dg = blockIdx.x;
    const int t0 = ch * CHUNK;
    const int lo = (t0 - 2 > 0) ? (t0 - 2) : 0;

    __shared__ int sidx[CHUNK + 2];
    if (threadIdx.x < (unsigned)(t0 + CHUNK - lo))
        sidx[threadIdx.x] = idx[b * T_ + lo + threadIdx.x];
    __syncthreads();

    const int i = dg * THREADS + threadIdx.x;
    float acc[8];
#pragma unroll
    for (int j = 0; j < 8; ++j) acc[j] = 0.0f;

#pragma unroll 4
    for (int k = 0; k < CHUNK; ++k) {
        int t = t0 + k;
        int r1 = sidx[t - lo];
        unsigned ub1 = g_P1[r1 * ROWB + i];
        unsigned n8 = 0; float magp = 1.0f, magn = -0.4f;
        if (t >= 2) {
            int r2 = sidx[t - 1 - lo], r3 = sidx[t - 2 - lo];
            n8 = (unsigned)(g_P2[r2 * ROWB + i] ^ g_P3[r3 * ROWB + i]);
        } else { magp = 0.3f; magn = 0.3f; }
        bind_step(ub1, n8, magp, magn, acc);
    }

    float* S = g_S + (size_t)(b * NCH + ch) * D_ + (size_t)i * 8;
    ((float4*)S)[0] = make_float4(acc[0], acc[1], acc[2], acc[3]);
    ((float4*)S)[1] = make_float4(acc[4], acc[5], acc[6], acc[7]);
}

__global__ __launch_bounds__(256) void carry_kernel() {
    int g = blockIdx.x * 256 + threadIdx.x;       // 0 .. B_*D_-1
    int b = g >> 12;                              // / D_
    int d = g & (D_ - 1);
    float dch = powf(DEC, (float)CHUNK);          // 0.95^32
    float c = 0.0f;
#pragma unroll 8
    for (int ch = 0; ch < NCH; ++ch) {
        size_t o = (size_t)(b * NCH + ch) * D_ + d;
        g_C[o] = c;
        c = fmaf(c, dch, g_S[o]);
    }
}

__global__ __launch_bounds__(THREADS) void emit_kernel(const int* __restrict__ idx,
                                                       float* __restrict__ out) {
    const int b  = blockIdx.z;
    const int ch = blockIdx.y;
    const int dg = blockIdx.x;
    const int t0 = ch * CHUNK;
    const int lo = (t0 - 2 > 0) ? (t0 - 2) : 0;

    __shared__ int   sidx[CHUNK + 2];
    __shared__ float sinv[CHUNK];
    if (threadIdx.x < (unsigned)(t0 + CHUNK - lo))
        sidx[threadIdx.x] = idx[b * T_ + lo + threadIdx.x];
    if (threadIdx.x < CHUNK)
        sinv[threadIdx.x] = g_invn[t0 + threadIdx.x];
    __syncthreads();

    const int i = dg * THREADS + threadIdx.x;

    const float* C = g_C + (size_t)(b * NCH + ch) * D_ + (size_t)i * 8;
    float4 c0 = ((const float4*)C)[0];
    float4 c1 = ((const float4*)C)[1];
    float acc[8] = {c0.x, c0.y, c0.z, c0.w, c1.x, c1.y, c1.z, c1.w};

    float* ob = out + (size_t)(b * T_) * D_ + (size_t)i * 8;
#pragma unroll 4
    for (int k = 0; k < CHUNK; ++k) {
        int t = t0 + k;
        int r1 = sidx[t - lo];
        unsigned ub1 = g_P1[r1 * ROWB + i];
        unsigned n8 = 0; float magp = 1.0f, magn = -0.4f;
        if (t >= 2) {
            int r2 = sidx[t - 1 - lo], r3 = sidx[t - 2 - lo];
            n8 = (unsigned)(g_P2[r2 * ROWB + i] ^ g_P3[r3 * ROWB + i]);
        } else { magp = 0.3f; magn = 0.3f; }
        bind_step(ub1, n8, magp, magn, acc);

        float invn = sinv[k];
        float4* o = (float4*)(ob + (size_t)t * D_);
        o[0] = make_float4(acc[0]*invn, acc[1]*invn, acc[2]*invn, acc[3]*invn);
        o[1] = make_float4(acc[4]*invn, acc[5]*invn, acc[6]*invn, acc[7]*invn);
    }
}

extern "C" void kernel_launch(void* const* d_in, const int* in_sizes, int n_in,
                              void* d_out, int out_size, void* d_ws, size_t ws_size,
                              hipStream_t stream) {
    const float* cb  = (const float*)d_in[0];   // (256, 4096) fp32
    const int*   idx = (const int*)d_in[1];     // (8, 2048) int32
    float*       out = (float*)d_out;           // (8, 2048, 4096) fp32

    pack_kernel  <<<dim3((VOCAB * ROWB) / 256), dim3(256), 0, stream>>>(cb);
    states_kernel<<<dim3(DGRP, NCH, B_), dim3(THREADS), 0, stream>>>(idx);
    carry_kernel <<<dim3((B_ * D_) / 256), dim3(256), 0, stream>>>();
    emit_kernel  <<<dim3(DGRP, NCH, B_), dim3(THREADS), 0, stream>>>(idx, out);
}